// Round 1
// baseline (273.009 us; speedup 1.0000x reference)
//
#include <hip/hip_runtime.h>

// TransformerDecoderLayer: B=4,S=2048,D=512,H=8,DK=64,DFF=2048, fp32 in/out.
// Pipeline: bf16 MFMA GEMMs (16x16x32) + swapped-QK^T flash attention + fp32 LN.

typedef __bf16 bf16x8 __attribute__((ext_vector_type(8)));
typedef float f32x4 __attribute__((ext_vector_type(4)));
typedef unsigned short us4 __attribute__((ext_vector_type(4)));

__device__ __forceinline__ unsigned short f2bf(float f){
  unsigned u = __builtin_bit_cast(unsigned, f);
  u += 0x7fffu + ((u >> 16) & 1u);   // RNE
  return (unsigned short)(u >> 16);
}

// ---------- f32 -> bf16 convert (4 elems/thread) ----------
__global__ void k_f2b(const float* __restrict__ in, unsigned short* __restrict__ out, int n4){
  int i = blockIdx.x * 256 + threadIdx.x;
  if (i < n4){
    float4 v = reinterpret_cast<const float4*>(in)[i];
    us4 o = { f2bf(v.x), f2bf(v.y), f2bf(v.z), f2bf(v.w) };
    reinterpret_cast<us4*>(out)[i] = o;
  }
}

// ---------- weight transpose+convert: in[K][N] f32 -> out[N][K] bf16 ----------
__global__ void k_wtrans(const float* __restrict__ in, unsigned short* __restrict__ out, int K, int N){
  __shared__ float t[32][33];
  int k0 = blockIdx.x*32, n0 = blockIdx.y*32;
  int tx = threadIdx.x & 31, ty = threadIdx.x >> 5;
  #pragma unroll
  for (int r = 0; r < 4; ++r)
    t[ty + 8*r][tx] = in[(size_t)(k0 + ty + 8*r)*N + n0 + tx];
  __syncthreads();
  #pragma unroll
  for (int r = 0; r < 4; ++r)
    out[(size_t)(n0 + ty + 8*r)*K + k0 + tx] = f2bf(t[tx][ty + 8*r]);
}

// qkv weights [H,512,64] (x3) -> Wt_qkv[1536][512], row n = sel*512 + h*64 + e
__global__ void k_wtrans_qkv(const float* __restrict__ qw, const float* __restrict__ kw,
                             const float* __restrict__ vw, unsigned short* __restrict__ out){
  __shared__ float t[32][33];
  int z = blockIdx.z, sel = z >> 3, h = z & 7;
  const float* in = (sel==0 ? qw : (sel==1 ? kw : vw)) + (size_t)h*512*64;
  unsigned short* o = out + ((size_t)(sel*512 + h*64)) * 512;
  int k0 = blockIdx.x*32, n0 = blockIdx.y*32;
  int tx = threadIdx.x & 31, ty = threadIdx.x >> 5;
  #pragma unroll
  for (int r = 0; r < 4; ++r)
    t[ty + 8*r][tx] = in[(size_t)(k0 + ty + 8*r)*64 + n0 + tx];
  __syncthreads();
  #pragma unroll
  for (int r = 0; r < 4; ++r)
    o[(size_t)(n0 + ty + 8*r)*512 + k0 + tx] = f2bf(t[tx][ty + 8*r]);
}

__global__ void k_bqkv(const float* __restrict__ qb, const float* __restrict__ kb,
                       const float* __restrict__ vb, float* __restrict__ out){
  int n = blockIdx.x*256 + threadIdx.x;
  if (n < 1536){ int sel = n >> 9, r = n & 511;
    out[n] = (sel==0 ? qb : (sel==1 ? kb : vb))[r]; }
}

// ---------- GEMM: C[M,N] = A[M,K](bf16) * Bt[N,K]^T (bf16) + bias, fused epilogues ----------
// MODE 0: QKV scatter -> Q[bh,s,e], K[bh,s,e], Vt[bh,e,s] (bf16)
// MODE 1: of = acc + bias + resid (f32)      (O-proj + residual)
// MODE 2: ob0 = bf16(relu(acc + bias))       (FF1)
// MODE 3: of = acc + bias + resid (f32)      (FF2 + residual)
template<int MODE>
__global__ __launch_bounds__(256) void k_gemm(
    const unsigned short* __restrict__ A, const unsigned short* __restrict__ Bt,
    const float* __restrict__ bias, const float* __restrict__ resid,
    unsigned short* __restrict__ ob0, unsigned short* __restrict__ ob1, unsigned short* __restrict__ ob2,
    float* __restrict__ of, int M, int N, int K)
{
  __shared__ unsigned short As[128][40];   // +8 pad: conflict-free b128 frag reads
  __shared__ unsigned short Bs[128][40];
  const int tid = threadIdx.x, lane = tid & 63, wid = tid >> 6;
  const int g = lane >> 4, lr = lane & 15;
  const int rowBase = blockIdx.x * 128, colBase = blockIdx.y * 128;
  const int wr = (wid >> 1) * 64, wc = (wid & 1) * 64;
  f32x4 acc[4][4] = {};
  for (int k0 = 0; k0 < K; k0 += 32){
    __syncthreads();
    #pragma unroll
    for (int i = 0; i < 2; ++i){
      int c = tid + 256*i, r = c >> 2, cb = (c & 3)*8;
      *reinterpret_cast<int4*>(&As[r][cb]) =
        *reinterpret_cast<const int4*>(A + (size_t)(rowBase + r)*K + k0 + cb);
      *reinterpret_cast<int4*>(&Bs[r][cb]) =
        *reinterpret_cast<const int4*>(Bt + (size_t)(colBase + r)*K + k0 + cb);
    }
    __syncthreads();
    bf16x8 af[4], bfr[4];
    #pragma unroll
    for (int mi = 0; mi < 4; ++mi) af[mi]  = *reinterpret_cast<const bf16x8*>(&As[wr + mi*16 + lr][g*8]);
    #pragma unroll
    for (int ni = 0; ni < 4; ++ni) bfr[ni] = *reinterpret_cast<const bf16x8*>(&Bs[wc + ni*16 + lr][g*8]);
    #pragma unroll
    for (int mi = 0; mi < 4; ++mi)
      #pragma unroll
      for (int ni = 0; ni < 4; ++ni)
        acc[mi][ni] = __builtin_amdgcn_mfma_f32_16x16x32_bf16(af[mi], bfr[ni], acc[mi][ni], 0, 0, 0);
  }
  float bv[4];
  #pragma unroll
  for (int ni = 0; ni < 4; ++ni) bv[ni] = bias[colBase + wc + ni*16 + lr];
  #pragma unroll
  for (int mi = 0; mi < 4; ++mi){
    #pragma unroll
    for (int ni = 0; ni < 4; ++ni){
      #pragma unroll
      for (int j = 0; j < 4; ++j){
        int m = rowBase + wr + mi*16 + g*4 + j;   // C/D: row=(lane>>4)*4+reg, col=lane&15
        int n = colBase + wc + ni*16 + lr;
        float v = acc[mi][ni][j] + bv[ni];
        if constexpr (MODE == 0){
          int b = m >> 11, s = m & 2047;
          int sel = n >> 9, rr = n & 511, h = rr >> 6, e = rr & 63;
          size_t bh = (size_t)(b*8 + h);
          if (sel == 0)      ob0[(bh*2048 + s)*64 + e] = f2bf(v);
          else if (sel == 1) ob1[(bh*2048 + s)*64 + e] = f2bf(v);
          else               ob2[(bh*64 + e)*2048 + s] = f2bf(v);   // V transposed
        } else if constexpr (MODE == 1 || MODE == 3){
          of[(size_t)m*N + n] = v + resid[(size_t)m*N + n];
        } else {
          ob0[(size_t)m*N + n] = f2bf(v > 0.f ? v : 0.f);
        }
      }
    }
  }
}

// ---------- flash attention, swapped QK^T (S^T = K*Q^T) ----------
// grid (qtile=32, bh=32), block 256 = 4 waves; wave owns 16 q rows.
__global__ __launch_bounds__(256) void k_attn(
    const unsigned short* __restrict__ Qb, const unsigned short* __restrict__ Kb,
    const unsigned short* __restrict__ Vt, const int* __restrict__ mask,
    unsigned short* __restrict__ ctx)
{
  __shared__ unsigned short Ks[64][72];
  __shared__ unsigned short Vs[64][72];
  __shared__ unsigned short Ps[4][16][72];   // per-wave P[q][k]
  const int tid = threadIdx.x, lane = tid & 63, wid = tid >> 6;
  const int g = lane >> 4, lr = lane & 15;
  const int qt = blockIdx.x, bh = blockIdx.y;
  const int b = bh >> 3, h = bh & 7;
  const int qw = qt * 64 + wid * 16;
  const size_t mbase = (size_t)b * 2048 * 2048;

  bf16x8 b_q[2];   // Q as B-operand: col q = lane&15, k(e) = 8*(lane>>4)+j
  {
    const unsigned short* qp = Qb + ((size_t)bh*2048 + qw + lr)*64;
    b_q[0] = *reinterpret_cast<const bf16x8*>(qp + g*8);
    b_q[1] = *reinterpret_cast<const bf16x8*>(qp + 32 + g*8);
  }
  f32x4 acc[4] = {};               // ctx^T frags: row e = ne*16+4g+j, col q = lr
  float m_run = -3.0e38f, l_run = 0.f;

  for (int kt = 0; kt < 32; ++kt){
    const int kk0 = kt * 64;
    __syncthreads();
    #pragma unroll
    for (int i = 0; i < 2; ++i){
      int c = tid + 256*i, r = c >> 3, cb = (c & 7)*8;
      *reinterpret_cast<int4*>(&Ks[r][cb]) =
        *reinterpret_cast<const int4*>(Kb + ((size_t)bh*2048 + kk0 + r)*64 + cb);
      *reinterpret_cast<int4*>(&Vs[r][cb]) =
        *reinterpret_cast<const int4*>(Vt + ((size_t)bh*64 + r)*2048 + kk0 + cb);
    }
    __syncthreads();
    // mask fast-path check: wave's 16 q rows x 64 k cols, vectorized
    int mok = 1;
    {
      const int* mp = mask + mbase + (size_t)(qw + (lane >> 2))*2048 + kk0 + (lane & 3)*16;
      #pragma unroll
      for (int i = 0; i < 4; ++i){
        int4 mv = *reinterpret_cast<const int4*>(mp + i*4);
        mok &= (mv.x != 0) & (mv.y != 0) & (mv.z != 0) & (mv.w != 0);
      }
    }
    bool fastp = __all(mok);
    // S^T = K * Q^T   (A = K rows; lane row k = mk*16+4g+j, col q = lr)
    f32x4 st[4] = {};
    #pragma unroll
    for (int mk = 0; mk < 4; ++mk)
      #pragma unroll
      for (int ks = 0; ks < 2; ++ks)
        st[mk] = __builtin_amdgcn_mfma_f32_16x16x32_bf16(
            *reinterpret_cast<const bf16x8*>(&Ks[mk*16 + lr][ks*32 + g*8]), b_q[ks], st[mk], 0,0,0);
    float sv[16];
    #pragma unroll
    for (int mk = 0; mk < 4; ++mk)
      #pragma unroll
      for (int j = 0; j < 4; ++j)
        sv[mk*4+j] = st[mk][j] * 0.125f;   // 1/sqrt(64)
    if (!fastp){
      #pragma unroll
      for (int mk = 0; mk < 4; ++mk)
        #pragma unroll
        for (int j = 0; j < 4; ++j){
          int kg = kk0 + mk*16 + g*4 + j;
          if (mask[mbase + (size_t)(qw + lr)*2048 + kg] == 0) sv[mk*4+j] = -1.25e19f;
        }
    }
    // online softmax over k; lane holds 16 values, all for q = lr
    float tm = sv[0];
    #pragma unroll
    for (int i = 1; i < 16; ++i) tm = fmaxf(tm, sv[i]);
    tm = fmaxf(tm, __shfl_xor(tm, 16));
    tm = fmaxf(tm, __shfl_xor(tm, 32));
    float mnew = fmaxf(m_run, tm);
    float alpha = __expf(m_run - mnew);
    float ps = 0.f;
    unsigned short pb[16];
    #pragma unroll
    for (int i = 0; i < 16; ++i){ float p = __expf(sv[i] - mnew); ps += p; pb[i] = f2bf(p); }
    ps += __shfl_xor(ps, 16);
    ps += __shfl_xor(ps, 32);
    l_run = l_run * alpha + ps;
    m_run = mnew;
    #pragma unroll
    for (int ne = 0; ne < 4; ++ne)
      #pragma unroll
      for (int j = 0; j < 4; ++j) acc[ne][j] *= alpha;
    // P[q][k] write: 4 consecutive k per mk -> b64
    #pragma unroll
    for (int mk = 0; mk < 4; ++mk){
      uint2 uu;
      uu.x = (unsigned)pb[mk*4+0] | ((unsigned)pb[mk*4+1] << 16);
      uu.y = (unsigned)pb[mk*4+2] | ((unsigned)pb[mk*4+3] << 16);
      *reinterpret_cast<uint2*>(&Ps[wid][lr][mk*16 + g*4]) = uu;
    }
    __syncthreads();   // order P writes before cross-lane P reads (also covers Ks/Vs reuse)
    // ctx^T += Vt * P^T : A = Vt rows e; B col q = lr, k contiguous from Ps[q][k]
    #pragma unroll
    for (int ks = 0; ks < 2; ++ks){
      bf16x8 pf = *reinterpret_cast<const bf16x8*>(&Ps[wid][lr][ks*32 + g*8]);
      #pragma unroll
      for (int ne = 0; ne < 4; ++ne)
        acc[ne] = __builtin_amdgcn_mfma_f32_16x16x32_bf16(
            *reinterpret_cast<const bf16x8*>(&Vs[ne*16 + lr][ks*32 + g*8]), pf, acc[ne], 0,0,0);
    }
  }
  float inv = 1.f / l_run;
  #pragma unroll
  for (int ne = 0; ne < 4; ++ne)
    #pragma unroll
    for (int j = 0; j < 4; ++j){
      int e = ne*16 + g*4 + j;
      int q = qw + lr;
      ctx[((size_t)b*2048 + q)*512 + h*64 + e] = f2bf(acc[ne][j] * inv);
    }
}

// ---------- LayerNorm: wave per row of 512 ----------
__global__ __launch_bounds__(256) void k_ln(
    const float* __restrict__ in, const float* __restrict__ gma, const float* __restrict__ bta,
    float* __restrict__ of, unsigned short* __restrict__ ob)
{
  const int lane = threadIdx.x & 63, wid = threadIdx.x >> 6;
  const size_t row = (size_t)blockIdx.x * 4 + wid;
  const float* x = in + row * 512;
  const int e0 = lane * 8;
  float xv[8];
  *reinterpret_cast<float4*>(&xv[0]) = *reinterpret_cast<const float4*>(x + e0);
  *reinterpret_cast<float4*>(&xv[4]) = *reinterpret_cast<const float4*>(x + e0 + 4);
  float s = 0.f, ss = 0.f;
  #pragma unroll
  for (int i = 0; i < 8; ++i){ s += xv[i]; ss += xv[i]*xv[i]; }
  #pragma unroll
  for (int o = 1; o < 64; o <<= 1){ s += __shfl_xor(s, o); ss += __shfl_xor(ss, o); }
  float mu = s * (1.f/512.f);
  float var = ss * (1.f/512.f) - mu*mu;
  float rs = rsqrtf(var + 1e-5f);
  float gv[8], bv[8], y[8];
  *reinterpret_cast<float4*>(&gv[0]) = *reinterpret_cast<const float4*>(gma + e0);
  *reinterpret_cast<float4*>(&gv[4]) = *reinterpret_cast<const float4*>(gma + e0 + 4);
  *reinterpret_cast<float4*>(&bv[0]) = *reinterpret_cast<const float4*>(bta + e0);
  *reinterpret_cast<float4*>(&bv[4]) = *reinterpret_cast<const float4*>(bta + e0 + 4);
  #pragma unroll
  for (int i = 0; i < 8; ++i) y[i] = (xv[i]-mu)*rs*gv[i] + bv[i];
  *reinterpret_cast<float4*>(of + row*512 + e0)     = *reinterpret_cast<float4*>(&y[0]);
  *reinterpret_cast<float4*>(of + row*512 + e0 + 4) = *reinterpret_cast<float4*>(&y[4]);
  if (ob){
    us4 o0 = { f2bf(y[0]), f2bf(y[1]), f2bf(y[2]), f2bf(y[3]) };
    us4 o1 = { f2bf(y[4]), f2bf(y[5]), f2bf(y[6]), f2bf(y[7]) };
    *reinterpret_cast<us4*>(ob + row*512 + e0)     = o0;
    *reinterpret_cast<us4*>(ob + row*512 + e0 + 4) = o1;
  }
}

extern "C" void kernel_launch(void* const* d_in, const int* in_sizes, int n_in,
                              void* d_out, int out_size, void* d_ws, size_t ws_size,
                              hipStream_t stream)
{
  const float* src  = (const float*)d_in[0];
  const int*   mask = (const int*)d_in[1];
  const float* q_w  = (const float*)d_in[2];
  const float* q_b  = (const float*)d_in[3];
  const float* k_w  = (const float*)d_in[4];
  const float* k_b  = (const float*)d_in[5];
  const float* v_w  = (const float*)d_in[6];
  const float* v_b  = (const float*)d_in[7];
  const float* o_w  = (const float*)d_in[8];
  const float* o_b  = (const float*)d_in[9];
  const float* ln1g = (const float*)d_in[10];
  const float* ln1b = (const float*)d_in[11];
  const float* w1   = (const float*)d_in[12];
  const float* b1   = (const float*)d_in[13];
  const float* w2   = (const float*)d_in[14];
  const float* b2   = (const float*)d_in[15];
  const float* ln2g = (const float*)d_in[16];
  const float* ln2b = (const float*)d_in[17];

  char* ws = (char*)d_ws;
  if (ws_size < 81795072) return;  // fail loudly rather than corrupt
  unsigned short* x_bf  = (unsigned short*)(ws + 0);          // 8.4MB (reused as LN1 bf16 out)
  unsigned short* wtqkv = (unsigned short*)(ws + 8388608);
  float*          bqkv  = (float*)(ws + 9961472);
  unsigned short* wto   = (unsigned short*)(ws + 9967616);
  unsigned short* wt1   = (unsigned short*)(ws + 10491904);
  unsigned short* wt2   = (unsigned short*)(ws + 12589056);
  unsigned short* Qb    = (unsigned short*)(ws + 14686208);
  unsigned short* Kb    = (unsigned short*)(ws + 23074816);
  unsigned short* Vt    = (unsigned short*)(ws + 31463424);
  unsigned short* ctx   = (unsigned short*)(ws + 39852032);
  unsigned short* ffb   = (unsigned short*)(ws + 14686208);   // overlays Q/K/Vt/ctx (dead)
  float* res = (float*)(ws + 48240640);                        // res1 then res2
  float* xf  = (float*)(ws + 65017856);
  float* outf = (float*)d_out;

  k_f2b<<<4096, 256, 0, stream>>>(src, x_bf, 1048576);
  k_wtrans_qkv<<<dim3(16,2,24), 256, 0, stream>>>(q_w, k_w, v_w, wtqkv);
  k_bqkv<<<6, 256, 0, stream>>>(q_b, k_b, v_b, bqkv);
  k_wtrans<<<dim3(16,16), 256, 0, stream>>>(o_w, wto, 512, 512);
  k_wtrans<<<dim3(16,64), 256, 0, stream>>>(w1, wt1, 512, 2048);
  k_wtrans<<<dim3(64,16), 256, 0, stream>>>(w2, wt2, 2048, 512);

  k_gemm<0><<<dim3(64,12), 256, 0, stream>>>(x_bf, wtqkv, bqkv, nullptr,
                                             Qb, Kb, Vt, nullptr, 8192, 1536, 512);
  k_attn<<<dim3(32,32), 256, 0, stream>>>(Qb, Kb, Vt, mask, ctx);
  k_gemm<1><<<dim3(64,4), 256, 0, stream>>>(ctx, wto, o_b, src,
                                            nullptr, nullptr, nullptr, res, 8192, 512, 512);
  k_ln<<<2048, 256, 0, stream>>>(res, ln1g, ln1b, xf, x_bf);
  k_gemm<2><<<dim3(64,16), 256, 0, stream>>>(x_bf, wt1, b1, nullptr,
                                             ffb, nullptr, nullptr, nullptr, 8192, 2048, 512);
  k_gemm<3><<<dim3(64,4), 256, 0, stream>>>(ffb, wt2, b2, xf,
                                            nullptr, nullptr, nullptr, res, 8192, 512, 2048);
  k_ln<<<2048, 256, 0, stream>>>(res, ln2g, ln2b, outf, nullptr);
}

// Round 2
// 237.306 us; speedup vs baseline: 1.1505x; 1.1505x over previous
//
#include <hip/hip_runtime.h>

// TransformerDecoderLayer: B=4,S=2048,D=512,H=8,DK=64,DFF=2048, fp32 in/out.
// bf16 MFMA GEMMs (global_load_lds staging + XOR chunk swizzle) +
// swapped-QK^T flash attention (mask bitmap + T14 reg prefetch + T13 defer-max) + fp32 LN.

typedef __bf16 bf16x8 __attribute__((ext_vector_type(8)));
typedef float f32x4 __attribute__((ext_vector_type(4)));
typedef unsigned short us4 __attribute__((ext_vector_type(4)));

__device__ __forceinline__ unsigned short f2bf(float f){
  unsigned u = __builtin_bit_cast(unsigned, f);
  u += 0x7fffu + ((u >> 16) & 1u);   // RNE
  return (unsigned short)(u >> 16);
}

typedef const __attribute__((address_space(1))) void* gas_t;
typedef __attribute__((address_space(3))) void* las_t;
__device__ __forceinline__ void gl_lds16(const void* g, void* l){
  // async global->LDS, 16B/lane; LDS dest = wave-uniform base + lane*16
  __builtin_amdgcn_global_load_lds((gas_t)g, (las_t)l, 16, 0, 0);
}

// ---------- f32 -> bf16 convert (4 elems/thread) ----------
__global__ void k_f2b(const float* __restrict__ in, unsigned short* __restrict__ out, int n4){
  int i = blockIdx.x * 256 + threadIdx.x;
  if (i < n4){
    float4 v = reinterpret_cast<const float4*>(in)[i];
    us4 o = { f2bf(v.x), f2bf(v.y), f2bf(v.z), f2bf(v.w) };
    reinterpret_cast<us4*>(out)[i] = o;
  }
}

// ---------- weight transpose+convert: in[K][N] f32 -> out[N][K] bf16 ----------
__global__ void k_wtrans(const float* __restrict__ in, unsigned short* __restrict__ out, int K, int N){
  __shared__ float t[32][33];
  int k0 = blockIdx.x*32, n0 = blockIdx.y*32;
  int tx = threadIdx.x & 31, ty = threadIdx.x >> 5;
  #pragma unroll
  for (int r = 0; r < 4; ++r)
    t[ty + 8*r][tx] = in[(size_t)(k0 + ty + 8*r)*N + n0 + tx];
  __syncthreads();
  #pragma unroll
  for (int r = 0; r < 4; ++r)
    out[(size_t)(n0 + ty + 8*r)*K + k0 + tx] = f2bf(t[tx][ty + 8*r]);
}

// qkv weights [H,512,64] (x3) -> Wt_qkv[1536][512], row n = sel*512 + h*64 + e
__global__ void k_wtrans_qkv(const float* __restrict__ qw, const float* __restrict__ kw,
                             const float* __restrict__ vw, unsigned short* __restrict__ out){
  __shared__ float t[32][33];
  int z = blockIdx.z, sel = z >> 3, h = z & 7;
  const float* in = (sel==0 ? qw : (sel==1 ? kw : vw)) + (size_t)h*512*64;
  unsigned short* o = out + ((size_t)(sel*512 + h*64)) * 512;
  int k0 = blockIdx.x*32, n0 = blockIdx.y*32;
  int tx = threadIdx.x & 31, ty = threadIdx.x >> 5;
  #pragma unroll
  for (int r = 0; r < 4; ++r)
    t[ty + 8*r][tx] = in[(size_t)(k0 + ty + 8*r)*64 + n0 + tx];
  __syncthreads();
  #pragma unroll
  for (int r = 0; r < 4; ++r)
    o[(size_t)(n0 + ty + 8*r)*512 + k0 + tx] = f2bf(t[tx][ty + 8*r]);
}

__global__ void k_bqkv(const float* __restrict__ qb, const float* __restrict__ kb,
                       const float* __restrict__ vb, float* __restrict__ out){
  int n = blockIdx.x*256 + threadIdx.x;
  if (n < 1536){ int sel = n >> 9, r = n & 511;
    out[n] = (sel==0 ? qb : (sel==1 ? kb : vb))[r]; }
}

// ---------- mask tile bitmap: out16[b*32+qt][half] bit i = tile(qt, half*16+i) all-ones ----------
__global__ __launch_bounds__(256) void k_maskbits(const int* __restrict__ mask, unsigned short* __restrict__ out){
  const int tid = threadIdx.x;
  const int bq = blockIdx.x;            // b*32 + qt
  const int half = blockIdx.y;          // kt halves
  const int b = bq >> 5, qt = bq & 31;
  const int* base = mask + (size_t)b*2048*2048 + (size_t)(qt*64 + (tid>>4)*4)*2048 + (tid&15)*4;
  unsigned bits = 0;
  for (int i = 0; i < 16; ++i){
    const int* p = base + (half*16 + i)*64;
    int ok = 1;
    #pragma unroll
    for (int r = 0; r < 4; ++r){
      int4 v = *reinterpret_cast<const int4*>(p + (size_t)r*2048);
      ok &= (v.x!=0)&(v.y!=0)&(v.z!=0)&(v.w!=0);
    }
    bits |= (unsigned)ok << i;
  }
  #pragma unroll
  for (int o = 1; o < 64; o <<= 1) bits &= __shfl_xor(bits, o);
  __shared__ unsigned red[4];
  if ((tid & 63) == 0) red[tid >> 6] = bits;
  __syncthreads();
  if (tid == 0) out[bq*2 + half] = (unsigned short)(red[0]&red[1]&red[2]&red[3]);
}

// ---------- GEMM: C[M,N] = A[M,K](bf16) * Bt[N,K]^T (bf16) + bias, fused epilogues ----------
// global_load_lds staging, linear LDS [128][32] with chunk swizzle c ^= (r>>1)&3.
// MODE 0: QKV scatter -> Q[bh,s,e], K[bh,s,e], Vt[bh,e,s] (bf16)
// MODE 1: of = acc + bias + resid (f32)      (O-proj + residual)
// MODE 2: ob0 = bf16(relu(acc + bias))       (FF1)
// MODE 3: of = acc + bias + resid (f32)      (FF2 + residual)
template<int MODE>
__global__ __launch_bounds__(256, 3) void k_gemm(
    const unsigned short* __restrict__ A, const unsigned short* __restrict__ Bt,
    const float* __restrict__ bias, const float* __restrict__ resid,
    unsigned short* __restrict__ ob0, unsigned short* __restrict__ ob1, unsigned short* __restrict__ ob2,
    float* __restrict__ of, int M, int N, int K)
{
  __shared__ unsigned short As[128*32];   // linear [128][32]
  __shared__ unsigned short Bs[128*32];
  const int tid = threadIdx.x, lane = tid & 63, wid = tid >> 6;
  const int g = lane >> 4, lr = lane & 15;
  const int rowBase = blockIdx.x * 128, colBase = blockIdx.y * 128;
  const int wr = (wid >> 1) * 64, wc = (wid & 1) * 64;
  // staging: wave wid instr t covers rows wid*32+t*16 .. +15; swizzled source column
  const int srow = wid*32 + (lane >> 2);
  const int gcol = ((lane & 3) ^ ((lane >> 3) & 3)) * 8;   // shorts
  const int rchunk = (g ^ ((lr >> 1) & 3)) * 8;            // frag read column (shorts)
  unsigned short* lA = &As[wid*1024];
  unsigned short* lB = &Bs[wid*1024];
  const unsigned short* pA = A + (size_t)(rowBase + srow)*K + gcol;
  const unsigned short* pB = Bt + (size_t)(colBase + srow)*K + gcol;
  f32x4 acc[4][4] = {};
  for (int k0 = 0; k0 < K; k0 += 32){
    __syncthreads();
    gl_lds16(pA + k0, lA);
    gl_lds16(pA + (size_t)16*K + k0, lA + 512);
    gl_lds16(pB + k0, lB);
    gl_lds16(pB + (size_t)16*K + k0, lB + 512);
    __syncthreads();   // compiler drains vmcnt before barrier -> staged data visible
    bf16x8 af[4], bfr[4];
    #pragma unroll
    for (int mi = 0; mi < 4; ++mi) af[mi]  = *reinterpret_cast<const bf16x8*>(&As[(wr + mi*16 + lr)*32 + rchunk]);
    #pragma unroll
    for (int ni = 0; ni < 4; ++ni) bfr[ni] = *reinterpret_cast<const bf16x8*>(&Bs[(wc + ni*16 + lr)*32 + rchunk]);
    #pragma unroll
    for (int mi = 0; mi < 4; ++mi)
      #pragma unroll
      for (int ni = 0; ni < 4; ++ni)
        acc[mi][ni] = __builtin_amdgcn_mfma_f32_16x16x32_bf16(af[mi], bfr[ni], acc[mi][ni], 0, 0, 0);
  }
  float bv[4];
  #pragma unroll
  for (int ni = 0; ni < 4; ++ni) bv[ni] = bias[colBase + wc + ni*16 + lr];
  #pragma unroll
  for (int mi = 0; mi < 4; ++mi){
    #pragma unroll
    for (int ni = 0; ni < 4; ++ni){
      #pragma unroll
      for (int j = 0; j < 4; ++j){
        int m = rowBase + wr + mi*16 + g*4 + j;   // C/D: row=(lane>>4)*4+reg, col=lane&15
        int n = colBase + wc + ni*16 + lr;
        float v = acc[mi][ni][j] + bv[ni];
        if constexpr (MODE == 0){
          int b = m >> 11, s = m & 2047;
          int sel = n >> 9, rr = n & 511, h = rr >> 6, e = rr & 63;
          size_t bh = (size_t)(b*8 + h);
          if (sel == 0)      ob0[(bh*2048 + s)*64 + e] = f2bf(v);
          else if (sel == 1) ob1[(bh*2048 + s)*64 + e] = f2bf(v);
          else               ob2[(bh*64 + e)*2048 + s] = f2bf(v);   // V transposed
        } else if constexpr (MODE == 1 || MODE == 3){
          of[(size_t)m*N + n] = v + resid[(size_t)m*N + n];
        } else {
          ob0[(size_t)m*N + n] = f2bf(v > 0.f ? v : 0.f);
        }
      }
    }
  }
}

// ---------- flash attention, swapped QK^T (S^T = K*Q^T) ----------
// grid (qtile=32, bh=32), block 256 = 4 waves; wave owns 16 q rows.
// T14 reg prefetch of next K/V tile; mask via precomputed bitmap; T13 defer-max.
__global__ __launch_bounds__(256) void k_attn(
    const unsigned short* __restrict__ Qb, const unsigned short* __restrict__ Kb,
    const unsigned short* __restrict__ Vt, const int* __restrict__ mask,
    const unsigned* __restrict__ mbits_p, unsigned short* __restrict__ ctx)
{
  __shared__ unsigned short Ks[64][72];
  __shared__ unsigned short Vs[64][72];
  __shared__ unsigned short Ps[4][16][72];   // per-wave P[q][k]
  const int tid = threadIdx.x, lane = tid & 63, wid = tid >> 6;
  const int g = lane >> 4, lr = lane & 15;
  const int qt = blockIdx.x, bh = blockIdx.y;
  const int b = bh >> 3, h = bh & 7;
  const int qw = qt * 64 + wid * 16;
  const unsigned mbits = mbits_p[b*32 + qt];
  const size_t mbase = (size_t)b * 2048 * 2048;
  const float SC = 0.18033688f;   // log2(e)/sqrt(64)

  bf16x8 b_q[2];   // Q as B-operand: col q = lane&15, k(e) = 8*(lane>>4)+j
  {
    const unsigned short* qp = Qb + ((size_t)bh*2048 + qw + lr)*64;
    b_q[0] = *reinterpret_cast<const bf16x8*>(qp + g*8);
    b_q[1] = *reinterpret_cast<const bf16x8*>(qp + 32 + g*8);
  }
  f32x4 acc[4] = {};               // ctx^T frags: row e = ne*16+4g+j, col q = lr
  float m_run = -3.0e38f, l_run = 0.f;

  // staging map: thread covers (r0,cb0) and (r1,cb1) 16B chunks of the 64x64 tile
  const int r0 = tid >> 3,        cb0 = (tid & 7)*8;
  const int r1 = 32 + (tid >> 3), cb1 = cb0;
  const unsigned short* kbase = Kb + (size_t)bh*2048*64;
  const unsigned short* vbase = Vt + (size_t)bh*64*2048;
  int4 kreg0, kreg1, vreg0, vreg1;

  kreg0 = *reinterpret_cast<const int4*>(kbase + (size_t)r0*64 + cb0);
  kreg1 = *reinterpret_cast<const int4*>(kbase + (size_t)r1*64 + cb1);
  vreg0 = *reinterpret_cast<const int4*>(vbase + (size_t)r0*2048 + cb0);
  vreg1 = *reinterpret_cast<const int4*>(vbase + (size_t)r1*2048 + cb1);
  *reinterpret_cast<int4*>(&Ks[r0][cb0]) = kreg0;
  *reinterpret_cast<int4*>(&Ks[r1][cb1]) = kreg1;
  *reinterpret_cast<int4*>(&Vs[r0][cb0]) = vreg0;
  *reinterpret_cast<int4*>(&Vs[r1][cb1]) = vreg1;
  __syncthreads();

  for (int kt = 0; kt < 32; ++kt){
    if (kt < 31){   // issue next-tile loads early (latency hides under compute)
      int nk = (kt + 1) * 64;
      kreg0 = *reinterpret_cast<const int4*>(kbase + (size_t)(nk + r0)*64 + cb0);
      kreg1 = *reinterpret_cast<const int4*>(kbase + (size_t)(nk + r1)*64 + cb1);
      vreg0 = *reinterpret_cast<const int4*>(vbase + (size_t)r0*2048 + nk + cb0);
      vreg1 = *reinterpret_cast<const int4*>(vbase + (size_t)r1*2048 + nk + cb1);
    }
    // S^T = K * Q^T   (A = K rows; lane row k = mk*16+4g+j, col q = lr)
    f32x4 st[4] = {};
    #pragma unroll
    for (int mk = 0; mk < 4; ++mk)
      #pragma unroll
      for (int ks = 0; ks < 2; ++ks)
        st[mk] = __builtin_amdgcn_mfma_f32_16x16x32_bf16(
            *reinterpret_cast<const bf16x8*>(&Ks[mk*16 + lr][ks*32 + g*8]), b_q[ks], st[mk], 0,0,0);
    float sv[16];
    #pragma unroll
    for (int mk = 0; mk < 4; ++mk)
      #pragma unroll
      for (int j = 0; j < 4; ++j) sv[mk*4+j] = st[mk][j];     // raw scores
    if (!((mbits >> kt) & 1)){
      const int kk0 = kt * 64;
      #pragma unroll
      for (int mk = 0; mk < 4; ++mk)
        #pragma unroll
        for (int j = 0; j < 4; ++j){
          int kg = kk0 + mk*16 + g*4 + j;
          if (mask[mbase + (size_t)(qw + lr)*2048 + kg] == 0) sv[mk*4+j] = -3.0e30f;
        }
    }
    // online softmax (log2 domain, scale folded); lane holds 16 values for q = lr
    float tm = sv[0];
    #pragma unroll
    for (int i = 1; i < 16; ++i) tm = fmaxf(tm, sv[i]);
    tm = fmaxf(tm, __shfl_xor(tm, 16));
    tm = fmaxf(tm, __shfl_xor(tm, 32));
    float tms = tm * SC;
    if (!__all(tms <= m_run + 8.f)){   // T13 defer-max, THR=8 (P bounded by 2^8)
      float mnew = fmaxf(m_run, tms);
      float alpha = exp2f(m_run - mnew);
      l_run *= alpha;
      #pragma unroll
      for (int ne = 0; ne < 4; ++ne)
        #pragma unroll
        for (int j = 0; j < 4; ++j) acc[ne][j] *= alpha;
      m_run = mnew;
    }
    float ps = 0.f;
    unsigned short pb[16];
    #pragma unroll
    for (int i = 0; i < 16; ++i){
      float p = exp2f(__builtin_fmaf(sv[i], SC, -m_run));
      ps += p; pb[i] = f2bf(p);
    }
    ps += __shfl_xor(ps, 16);
    ps += __shfl_xor(ps, 32);
    l_run += ps;
    // P[q][k] write (per-wave buffer; intra-wave lgkmcnt orders write->read, no barrier)
    #pragma unroll
    for (int mk = 0; mk < 4; ++mk){
      uint2 uu;
      uu.x = (unsigned)pb[mk*4+0] | ((unsigned)pb[mk*4+1] << 16);
      uu.y = (unsigned)pb[mk*4+2] | ((unsigned)pb[mk*4+3] << 16);
      *reinterpret_cast<uint2*>(&Ps[wid][lr][mk*16 + g*4]) = uu;
    }
    // ctx^T += Vt * P^T : A = Vt rows e; B col q = lr, k contiguous from Ps[q][k]
    #pragma unroll
    for (int ks = 0; ks < 2; ++ks){
      bf16x8 pf = *reinterpret_cast<const bf16x8*>(&Ps[wid][lr][ks*32 + g*8]);
      #pragma unroll
      for (int ne = 0; ne < 4; ++ne)
        acc[ne] = __builtin_amdgcn_mfma_f32_16x16x32_bf16(
            *reinterpret_cast<const bf16x8*>(&Vs[ne*16 + lr][ks*32 + g*8]), pf, acc[ne], 0,0,0);
    }
    if (kt < 31){
      __syncthreads();   // all waves done reading Ks/Vs
      *reinterpret_cast<int4*>(&Ks[r0][cb0]) = kreg0;
      *reinterpret_cast<int4*>(&Ks[r1][cb1]) = kreg1;
      *reinterpret_cast<int4*>(&Vs[r0][cb0]) = vreg0;
      *reinterpret_cast<int4*>(&Vs[r1][cb1]) = vreg1;
      __syncthreads();   // staged tile visible
    }
  }
  float inv = 1.f / l_run;
  #pragma unroll
  for (int ne = 0; ne < 4; ++ne)
    #pragma unroll
    for (int j = 0; j < 4; ++j){
      int e = ne*16 + g*4 + j;
      int q = qw + lr;
      ctx[((size_t)b*2048 + q)*512 + h*64 + e] = f2bf(acc[ne][j] * inv);
    }
}

// ---------- LayerNorm: wave per row of 512 ----------
__global__ __launch_bounds__(256) void k_ln(
    const float* __restrict__ in, const float* __restrict__ gma, const float* __restrict__ bta,
    float* __restrict__ of, unsigned short* __restrict__ ob)
{
  const int lane = threadIdx.x & 63, wid = threadIdx.x >> 6;
  const size_t row = (size_t)blockIdx.x * 4 + wid;
  const float* x = in + row * 512;
  const int e0 = lane * 8;
  float xv[8];
  *reinterpret_cast<float4*>(&xv[0]) = *reinterpret_cast<const float4*>(x + e0);
  *reinterpret_cast<float4*>(&xv[4]) = *reinterpret_cast<const float4*>(x + e0 + 4);
  float s = 0.f, ss = 0.f;
  #pragma unroll
  for (int i = 0; i < 8; ++i){ s += xv[i]; ss += xv[i]*xv[i]; }
  #pragma unroll
  for (int o = 1; o < 64; o <<= 1){ s += __shfl_xor(s, o); ss += __shfl_xor(ss, o); }
  float mu = s * (1.f/512.f);
  float var = ss * (1.f/512.f) - mu*mu;
  float rs = rsqrtf(var + 1e-5f);
  float gv[8], bv[8], y[8];
  *reinterpret_cast<float4*>(&gv[0]) = *reinterpret_cast<const float4*>(gma + e0);
  *reinterpret_cast<float4*>(&gv[4]) = *reinterpret_cast<const float4*>(gma + e0 + 4);
  *reinterpret_cast<float4*>(&bv[0]) = *reinterpret_cast<const float4*>(bta + e0);
  *reinterpret_cast<float4*>(&bv[4]) = *reinterpret_cast<const float4*>(bta + e0 + 4);
  #pragma unroll
  for (int i = 0; i < 8; ++i) y[i] = (xv[i]-mu)*rs*gv[i] + bv[i];
  *reinterpret_cast<float4*>(of + row*512 + e0)     = *reinterpret_cast<float4*>(&y[0]);
  *reinterpret_cast<float4*>(of + row*512 + e0 + 4) = *reinterpret_cast<float4*>(&y[4]);
  if (ob){
    us4 o0 = { f2bf(y[0]), f2bf(y[1]), f2bf(y[2]), f2bf(y[3]) };
    us4 o1 = { f2bf(y[4]), f2bf(y[5]), f2bf(y[6]), f2bf(y[7]) };
    *reinterpret_cast<us4*>(ob + row*512 + e0)     = o0;
    *reinterpret_cast<us4*>(ob + row*512 + e0 + 4) = o1;
  }
}

extern "C" void kernel_launch(void* const* d_in, const int* in_sizes, int n_in,
                              void* d_out, int out_size, void* d_ws, size_t ws_size,
                              hipStream_t stream)
{
  const float* src  = (const float*)d_in[0];
  const int*   mask = (const int*)d_in[1];
  const float* q_w  = (const float*)d_in[2];
  const float* q_b  = (const float*)d_in[3];
  const float* k_w  = (const float*)d_in[4];
  const float* k_b  = (const float*)d_in[5];
  const float* v_w  = (const float*)d_in[6];
  const float* v_b  = (const float*)d_in[7];
  const float* o_w  = (const float*)d_in[8];
  const float* o_b  = (const float*)d_in[9];
  const float* ln1g = (const float*)d_in[10];
  const float* ln1b = (const float*)d_in[11];
  const float* w1   = (const float*)d_in[12];
  const float* b1   = (const float*)d_in[13];
  const float* w2   = (const float*)d_in[14];
  const float* b2   = (const float*)d_in[15];
  const float* ln2g = (const float*)d_in[16];
  const float* ln2b = (const float*)d_in[17];

  char* ws = (char*)d_ws;
  if (ws_size < 81795072) return;
  unsigned short* x_bf  = (unsigned short*)(ws + 0);          // 8.4MB (reused as LN1 bf16 out)
  unsigned short* wtqkv = (unsigned short*)(ws + 8388608);
  float*          bqkv  = (float*)(ws + 9961472);
  unsigned short* wto   = (unsigned short*)(ws + 9967616);
  unsigned short* wt1   = (unsigned short*)(ws + 10491904);
  unsigned short* wt2   = (unsigned short*)(ws + 12589056);
  unsigned short* Qb    = (unsigned short*)(ws + 14686208);
  unsigned short* Kb    = (unsigned short*)(ws + 23074816);
  unsigned short* Vt    = (unsigned short*)(ws + 31463424);
  unsigned short* ctx   = (unsigned short*)(ws + 39852032);
  unsigned short* ffb   = (unsigned short*)(ws + 14686208);   // overlays Q/K/Vt/ctx (dead by FF1)
  float* res = (float*)(ws + 48240640);                        // res1 then res2
  float* xf  = (float*)(ws + 65017856);
  // mask bitmap lives in the first 512B of res: written at launch start, read by attn,
  // overwritten later by k_gemm<1> -- safe within each (deterministic) replay.
  unsigned short* mb16 = (unsigned short*)(ws + 48240640);
  const unsigned* mb32 = (const unsigned*)(ws + 48240640);
  float* outf = (float*)d_out;

  k_maskbits<<<dim3(128,2), 256, 0, stream>>>(mask, mb16);
  k_f2b<<<4096, 256, 0, stream>>>(src, x_bf, 1048576);
  k_wtrans_qkv<<<dim3(16,2,24), 256, 0, stream>>>(q_w, k_w, v_w, wtqkv);
  k_bqkv<<<6, 256, 0, stream>>>(q_b, k_b, v_b, bqkv);
  k_wtrans<<<dim3(16,16), 256, 0, stream>>>(o_w, wto, 512, 512);
  k_wtrans<<<dim3(16,64), 256, 0, stream>>>(w1, wt1, 512, 2048);
  k_wtrans<<<dim3(64,16), 256, 0, stream>>>(w2, wt2, 2048, 512);

  k_gemm<0><<<dim3(64,12), 256, 0, stream>>>(x_bf, wtqkv, bqkv, nullptr,
                                             Qb, Kb, Vt, nullptr, 8192, 1536, 512);
  k_attn<<<dim3(32,32), 256, 0, stream>>>(Qb, Kb, Vt, mask, mb32, ctx);
  k_gemm<1><<<dim3(64,4), 256, 0, stream>>>(ctx, wto, o_b, src,
                                            nullptr, nullptr, nullptr, res, 8192, 512, 512);
  k_ln<<<2048, 256, 0, stream>>>(res, ln1g, ln1b, xf, x_bf);
  k_gemm<2><<<dim3(64,16), 256, 0, stream>>>(x_bf, wt1, b1, nullptr,
                                             ffb, nullptr, nullptr, nullptr, 8192, 2048, 512);
  k_gemm<3><<<dim3(64,4), 256, 0, stream>>>(ffb, wt2, b2, xf,
                                            nullptr, nullptr, nullptr, res, 8192, 512, 2048);
  k_ln<<<2048, 256, 0, stream>>>(res, ln2g, ln2b, outf, nullptr);
}